// Round 1
// baseline (1406.409 us; speedup 1.0000x reference)
//
#include <hip/hip_runtime.h>
#include <cstdint>
#include <cstddef>

#define B_ 64
#define C_ 256
#define N_ 1024

// ---------------------------------------------------------------------------
// prep: BN scale/shift folding + concatenated Wqk/bqk
// ---------------------------------------------------------------------------
__global__ __launch_bounds__(256) void prep_kernel(
    const float* __restrict__ g1, const float* __restrict__ b1,
    const float* __restrict__ m1, const float* __restrict__ v1,
    const float* __restrict__ g2, const float* __restrict__ b2,
    const float* __restrict__ m2, const float* __restrict__ v2,
    const float* __restrict__ wq, const float* __restrict__ bq,
    const float* __restrict__ wk, const float* __restrict__ bk,
    float* __restrict__ scale1, float* __restrict__ shift1,
    float* __restrict__ scale2, float* __restrict__ shift2,
    float* __restrict__ Wqk, float* __restrict__ bqk) {
  const int t = threadIdx.x;
  {
    float s1 = g1[t] * rsqrtf(v1[t] + 1e-5f);
    scale1[t] = s1;
    shift1[t] = b1[t] - m1[t] * s1;
    float s2 = g2[t] * rsqrtf(v2[t] + 1e-5f);
    scale2[t] = s2;
    shift2[t] = b2[t] - m2[t] * s2;
  }
  if (t < 64) bqk[t] = (t < 32) ? bq[t] : bk[t - 32];
  for (int e = t; e < 64 * 256; e += 256) {
    int o = e >> 8, c = e & 255;
    Wqk[e] = (o < 32) ? wq[o * 256 + c] : wk[(o - 32) * 256 + c];
  }
}

// ---------------------------------------------------------------------------
// depthwise 3x3, SAME zero padding. One block per (b,c) 32x32 plane.
// ---------------------------------------------------------------------------
__global__ __launch_bounds__(256) void dw_conv(const float* __restrict__ in,
                                               const float* __restrict__ w,
                                               float* __restrict__ out) {
  const int plane = blockIdx.x;  // b*256 + c
  const int c = plane & 255;
  const float* wp = w + c * 9;
  const float w0 = wp[0], w1 = wp[1], w2 = wp[2];
  const float w3 = wp[3], w4 = wp[4], w5 = wp[5];
  const float w6 = wp[6], w7 = wp[7], w8 = wp[8];
  const size_t base = (size_t)plane * N_;
  const float* ip = in + base;
  float* op = out + base;
  for (int p = threadIdx.x; p < N_; p += 256) {
    const int h = p >> 5, x = p & 31;
    const bool ht = h > 0, hb = h < 31, xl = x > 0, xr = x < 31;
    float s = ip[p] * w4;
    if (ht) {
      s += ip[p - 32] * w1;
      if (xl) s += ip[p - 33] * w0;
      if (xr) s += ip[p - 31] * w2;
    }
    if (xl) s += ip[p - 1] * w3;
    if (xr) s += ip[p + 1] * w5;
    if (hb) {
      s += ip[p + 32] * w7;
      if (xl) s += ip[p + 31] * w6;
      if (xr) s += ip[p + 33] * w8;
    }
    op[p] = s;
  }
}

// ---------------------------------------------------------------------------
// generic pointwise GEMM: Y[b,o,n] = epi( sum_c W[o,c] * X[b,c,n] )
// EPI: 0 = BN+ReLU, 1 = BN, 2 = +bias only (scale unused), 3 = BN + resid
// Tile: 64 o x 64 n, K-step 16. 256 threads, 4x4 per thread.
// ---------------------------------------------------------------------------
template <int EPI>
__global__ __launch_bounds__(256) void pw_gemm(
    const float* __restrict__ X, const float* __restrict__ W, int O,
    const float* __restrict__ scale, const float* __restrict__ shift,
    const float* __restrict__ resid, float* __restrict__ Y) {
  const int n0 = blockIdx.x * 64;
  const int o0 = blockIdx.y * 64;
  const int b = blockIdx.z;
  const float* Xb = X + (size_t)b * C_ * N_;

  __shared__ float Ws[16][68];  // [k][o]
  __shared__ float Xs[16][68];  // [k][n]

  const int tid = threadIdx.x;
  const int tx = tid & 15, ty = tid >> 4;
  const int wo = tid >> 2, wk0 = (tid & 3) * 4;  // W-tile load mapping
  const int xk = tid >> 4, xn = (tid & 15) * 4;  // X-tile load mapping

  float acc[4][4] = {};

  for (int k0 = 0; k0 < C_; k0 += 16) {
    const float4 wv4 = *(const float4*)&W[(size_t)(o0 + wo) * C_ + k0 + wk0];
    const float4 xv4 = *(const float4*)&Xb[(size_t)(k0 + xk) * N_ + n0 + xn];
    Ws[wk0 + 0][wo] = wv4.x;
    Ws[wk0 + 1][wo] = wv4.y;
    Ws[wk0 + 2][wo] = wv4.z;
    Ws[wk0 + 3][wo] = wv4.w;
    *(float4*)&Xs[xk][xn] = xv4;
    __syncthreads();
#pragma unroll
    for (int kk = 0; kk < 16; ++kk) {
      const float4 wv = *(const float4*)&Ws[kk][ty * 4];
      const float4 xv = *(const float4*)&Xs[kk][tx * 4];
      const float wa[4] = {wv.x, wv.y, wv.z, wv.w};
      const float xa[4] = {xv.x, xv.y, xv.z, xv.w};
#pragma unroll
      for (int i = 0; i < 4; ++i)
#pragma unroll
        for (int j = 0; j < 4; ++j) acc[i][j] += wa[i] * xa[j];
    }
    __syncthreads();
  }

#pragma unroll
  for (int i = 0; i < 4; ++i) {
    const int o = o0 + ty * 4 + i;
    float sc, sh;
    if constexpr (EPI == 2) {
      sc = 1.f;
      sh = shift[o];
    } else {
      sc = scale[o];
      sh = shift[o];
    }
#pragma unroll
    for (int j = 0; j < 4; ++j) {
      const int n = n0 + tx * 4 + j;
      float y = acc[i][j] * sc + sh;
      if constexpr (EPI == 3) y += resid[((size_t)b * C_ + o) * N_ + n];
      if constexpr (EPI == 0) y = fmaxf(y, 0.f);
      Y[((size_t)b * O + o) * N_ + n] = y;
    }
  }
}

// ---------------------------------------------------------------------------
// attention pass A: per (b,m) row max and 1/sum(exp) with online softmax.
// qk buffer: [b][64][1024], rows 0..31 = q, rows 32..63 = k.
// ---------------------------------------------------------------------------
__global__ __launch_bounds__(256) void attn_stats(const float* __restrict__ qk,
                                                  float* __restrict__ rowmax,
                                                  float* __restrict__ invsum) {
  const int b = blockIdx.y;
  const int m = blockIdx.x * 256 + threadIdx.x;
  const float* qb = qk + (size_t)b * 64 * N_;
  const float* kb = qb + 32 * N_;

  float qr[32];
#pragma unroll
  for (int d = 0; d < 32; ++d) qr[d] = qb[d * N_ + m];

  __shared__ float Ks[128][36];  // [n][d]
  float M = -1e30f, S = 0.f;

  for (int n0 = 0; n0 < N_; n0 += 128) {
    __syncthreads();
    for (int e = threadIdx.x; e < 4096; e += 256) {
      const int d = e >> 7, n = e & 127;
      Ks[n][d] = kb[(size_t)d * N_ + n0 + n];
    }
    __syncthreads();
    for (int nn = 0; nn < 128; ++nn) {
      float s = 0.f;
#pragma unroll
      for (int j = 0; j < 8; ++j) {
        const float4 kv = *(const float4*)&Ks[nn][j * 4];
        s += qr[j * 4 + 0] * kv.x + qr[j * 4 + 1] * kv.y +
             qr[j * 4 + 2] * kv.z + qr[j * 4 + 3] * kv.w;
      }
      if (s > M) {
        S = S * __expf(M - s) + 1.f;
        M = s;
      } else {
        S += __expf(s - M);
      }
    }
  }
  rowmax[(size_t)b * N_ + m] = M;
  invsum[(size_t)b * N_ + m] = 1.f / S;
}

// ---------------------------------------------------------------------------
// attention pass B: out[b,c,m] = relu(gamma * invsum[m] * sum_n exp(s(m,n)-max[m]) * v[c,n] + a[b,c,m])
// Block tile: 64 m x 128 c, n-step 16. Recomputes s from q,k.
// ---------------------------------------------------------------------------
__global__ __launch_bounds__(256) void attn_out(
    const float* __restrict__ qk, const float* __restrict__ v,
    const float* __restrict__ a, const float* __restrict__ rowmax,
    const float* __restrict__ invsum, const float* __restrict__ gamma_p,
    float* __restrict__ out) {
  const int b = blockIdx.z;
  const int m0 = blockIdx.y * 64;
  const int c0 = blockIdx.x * 128;
  const int tid = threadIdx.x;
  const int tx = tid & 15, ty = tid >> 4;

  const float* qb = qk + (size_t)b * 64 * N_;
  const float* kb = qb + 32 * N_;
  const float* vb = v + (size_t)b * C_ * N_;

  __shared__ float Qs[64][36];   // [m][d]
  __shared__ float Ks[16][36];   // [n][d]
  __shared__ float Ps[16][68];   // [n][m]
  __shared__ float Vs[16][132];  // [n][c]

  for (int e = tid; e < 2048; e += 256) {
    const int d = e >> 6, mm = e & 63;
    Qs[mm][d] = qb[(size_t)d * N_ + m0 + mm];
  }

  float acc[4][8] = {};
  const int sm = tid >> 2, sn0 = (tid & 3) * 4;
  const float rmax = rowmax[(size_t)b * N_ + m0 + sm];

  for (int n0 = 0; n0 < N_; n0 += 16) {
    __syncthreads();
    // stage K tile [16 n][32 d]
    {
      const int d0 = tid >> 4, nn = tid & 15;
      Ks[nn][d0] = kb[(size_t)d0 * N_ + n0 + nn];
      Ks[nn][d0 + 16] = kb[(size_t)(d0 + 16) * N_ + n0 + nn];
    }
    // stage V tile [16 n][128 c]
    {
      const int cc = tid >> 2, nn4 = (tid & 3) * 4;
      const float4 va_ = *(const float4*)&vb[(size_t)(c0 + cc) * N_ + n0 + nn4];
      Vs[nn4 + 0][cc] = va_.x;
      Vs[nn4 + 1][cc] = va_.y;
      Vs[nn4 + 2][cc] = va_.z;
      Vs[nn4 + 3][cc] = va_.w;
      const float4 vc_ =
          *(const float4*)&vb[(size_t)(c0 + cc + 64) * N_ + n0 + nn4];
      Vs[nn4 + 0][cc + 64] = vc_.x;
      Vs[nn4 + 1][cc + 64] = vc_.y;
      Vs[nn4 + 2][cc + 64] = vc_.z;
      Vs[nn4 + 3][cc + 64] = vc_.w;
    }
    __syncthreads();
    // S tile: thread computes rows sm, cols sn0..sn0+3
    {
      float s0 = 0.f, s1 = 0.f, s2 = 0.f, s3 = 0.f;
#pragma unroll
      for (int j = 0; j < 8; ++j) {
        const float4 qv = *(const float4*)&Qs[sm][j * 4];
        const float4 ka = *(const float4*)&Ks[sn0 + 0][j * 4];
        const float4 kb4 = *(const float4*)&Ks[sn0 + 1][j * 4];
        const float4 kc = *(const float4*)&Ks[sn0 + 2][j * 4];
        const float4 kd = *(const float4*)&Ks[sn0 + 3][j * 4];
        s0 += qv.x * ka.x + qv.y * ka.y + qv.z * ka.z + qv.w * ka.w;
        s1 += qv.x * kb4.x + qv.y * kb4.y + qv.z * kb4.z + qv.w * kb4.w;
        s2 += qv.x * kc.x + qv.y * kc.y + qv.z * kc.z + qv.w * kc.w;
        s3 += qv.x * kd.x + qv.y * kd.y + qv.z * kd.z + qv.w * kd.w;
      }
      Ps[sn0 + 0][sm] = __expf(s0 - rmax);
      Ps[sn0 + 1][sm] = __expf(s1 - rmax);
      Ps[sn0 + 2][sm] = __expf(s2 - rmax);
      Ps[sn0 + 3][sm] = __expf(s3 - rmax);
    }
    __syncthreads();
#pragma unroll
    for (int nn = 0; nn < 16; ++nn) {
      const float4 pv = *(const float4*)&Ps[nn][tx * 4];
      const float4 v0 = *(const float4*)&Vs[nn][ty * 8];
      const float4 v1 = *(const float4*)&Vs[nn][ty * 8 + 4];
      const float p[4] = {pv.x, pv.y, pv.z, pv.w};
      const float vv[8] = {v0.x, v0.y, v0.z, v0.w, v1.x, v1.y, v1.z, v1.w};
#pragma unroll
      for (int mi = 0; mi < 4; ++mi)
#pragma unroll
        for (int cj = 0; cj < 8; ++cj) acc[mi][cj] += p[mi] * vv[cj];
    }
  }

  const float gma = gamma_p[0];
  float inv[4];
#pragma unroll
  for (int mi = 0; mi < 4; ++mi)
    inv[mi] = invsum[(size_t)b * N_ + m0 + tx * 4 + mi];

#pragma unroll
  for (int cj = 0; cj < 8; ++cj) {
    const int c = c0 + ty * 8 + cj;
    const float* ap = a + ((size_t)b * C_ + c) * N_ + m0;
    float* op = out + ((size_t)b * C_ + c) * N_ + m0;
#pragma unroll
    for (int mi = 0; mi < 4; ++mi) {
      const int mm = tx * 4 + mi;
      const float val = gma * acc[mi][cj] * inv[mi] + ap[mm];
      op[mm] = fmaxf(val, 0.f);
    }
  }
}

// ---------------------------------------------------------------------------
extern "C" void kernel_launch(void* const* d_in, const int* in_sizes, int n_in,
                              void* d_out, int out_size, void* d_ws,
                              size_t ws_size, hipStream_t stream) {
  const float* x = (const float*)d_in[0];
  const float* dw1 = (const float*)d_in[1];
  const float* pw1 = (const float*)d_in[2];
  const float* bn1g = (const float*)d_in[3];
  const float* bn1b = (const float*)d_in[4];
  const float* bn1m = (const float*)d_in[5];
  const float* bn1v = (const float*)d_in[6];
  const float* dw2 = (const float*)d_in[7];
  const float* pw2 = (const float*)d_in[8];
  const float* bn2g = (const float*)d_in[9];
  const float* bn2b = (const float*)d_in[10];
  const float* bn2m = (const float*)d_in[11];
  const float* bn2v = (const float*)d_in[12];
  const float* wq = (const float*)d_in[13];
  const float* bq = (const float*)d_in[14];
  const float* wk = (const float*)d_in[15];
  const float* bk = (const float*)d_in[16];
  const float* wv = (const float*)d_in[17];
  const float* bv = (const float*)d_in[18];
  const float* gamma = (const float*)d_in[19];
  float* out = (float*)d_out;

  float* ws = (float*)d_ws;
  const size_t PLANE = (size_t)B_ * C_ * N_;  // 16777216
  float* buf0 = ws;
  float* buf1 = buf0 + PLANE;
  float* qk = buf1 + PLANE;  // 64*64*1024
  float* rowmax = qk + (size_t)B_ * 64 * N_;
  float* invsum = rowmax + (size_t)B_ * N_;
  float* scale1 = invsum + (size_t)B_ * N_;
  float* shift1 = scale1 + 256;
  float* scale2 = shift1 + 256;
  float* shift2 = scale2 + 256;
  float* Wqk = shift2 + 256;
  float* bqk = Wqk + 64 * 256;

  prep_kernel<<<1, 256, 0, stream>>>(bn1g, bn1b, bn1m, bn1v, bn2g, bn2b, bn2m,
                                     bn2v, wq, bq, wk, bk, scale1, shift1,
                                     scale2, shift2, Wqk, bqk);
  // t1 = dw1(x)
  dw_conv<<<B_ * C_, 256, 0, stream>>>(x, dw1, buf0);
  // y1 = relu(BN1(pw1(t1)))
  pw_gemm<0><<<dim3(16, 4, B_), 256, 0, stream>>>(buf0, pw1, 256, scale1,
                                                  shift1, nullptr, buf1);
  // t2 = dw2(y1)
  dw_conv<<<B_ * C_, 256, 0, stream>>>(buf1, dw2, buf0);
  // a = BN2(pw2(t2)) + x
  pw_gemm<3><<<dim3(16, 4, B_), 256, 0, stream>>>(buf0, pw2, 256, scale2,
                                                  shift2, x, buf1);
  // qk = Wqk * a + bqk   (q rows 0..31, k rows 32..63)
  pw_gemm<2><<<dim3(16, 1, B_), 256, 0, stream>>>(buf1, Wqk, 64, nullptr, bqk,
                                                  nullptr, qk);
  // v = wv * a + bv
  pw_gemm<2><<<dim3(16, 4, B_), 256, 0, stream>>>(buf1, wv, 256, nullptr, bv,
                                                  nullptr, buf0);
  // softmax stats
  attn_stats<<<dim3(4, B_), 256, 0, stream>>>(qk, rowmax, invsum);
  // fused P*V + gamma*out + a + relu
  attn_out<<<dim3(2, 16, B_), 256, 0, stream>>>(qk, buf0, buf1, rowmax, invsum,
                                                gamma, out);
}

// Round 2
// 359.911 us; speedup vs baseline: 3.9077x; 3.9077x over previous
//
#include <hip/hip_runtime.h>
#include <cstdint>
#include <cstddef>

#define B_ 64
#define C_ 256
#define N_ 1024

typedef short v8s __attribute__((ext_vector_type(8)));
typedef float v4f __attribute__((ext_vector_type(4)));
typedef unsigned int u32;
typedef unsigned short u16;

__device__ __forceinline__ float bf2f(u16 u) {
  return __uint_as_float(((u32)u) << 16);
}
__device__ __forceinline__ u16 f2bf(float f) {
  u32 x = __float_as_uint(f);
  x += 0x7fffu + ((x >> 16) & 1u);
  return (u16)(x >> 16);
}
__device__ __forceinline__ u32 pack2(float a, float b) {
  return (u32)f2bf(a) | ((u32)f2bf(b) << 16);
}

// ---------------------------------------------------------------------------
// prep: BN folding, weight casts/concat/transposes
// ---------------------------------------------------------------------------
__global__ __launch_bounds__(256) void prep(
    const float* __restrict__ g1, const float* __restrict__ b1,
    const float* __restrict__ m1, const float* __restrict__ v1,
    const float* __restrict__ g2, const float* __restrict__ b2,
    const float* __restrict__ m2, const float* __restrict__ v2,
    const float* __restrict__ wq, const float* __restrict__ bq,
    const float* __restrict__ wk, const float* __restrict__ bk,
    const float* __restrict__ pw1, const float* __restrict__ pw2,
    const float* __restrict__ wv, const float* __restrict__ dw1,
    const float* __restrict__ dw2, float* __restrict__ scale1,
    float* __restrict__ shift1, float* __restrict__ scale2,
    float* __restrict__ shift2, float* __restrict__ bqk,
    float* __restrict__ dwT1, float* __restrict__ dwT2,
    u16* __restrict__ pw1b, u16* __restrict__ pw2b, u16* __restrict__ wvb,
    u16* __restrict__ wqkb) {
  const int gt = blockIdx.x * 256 + threadIdx.x;  // 16384 threads
  if (gt < 256) {
    float s1 = g1[gt] * rsqrtf(v1[gt] + 1e-5f);
    scale1[gt] = s1;
    shift1[gt] = b1[gt] - m1[gt] * s1;
    float s2 = g2[gt] * rsqrtf(v2[gt] + 1e-5f);
    scale2[gt] = s2;
    shift2[gt] = b2[gt] - m2[gt] * s2;
  }
  if (gt < 64) bqk[gt] = (gt < 32) ? bq[gt] : bk[gt - 32];
  if (gt < 2304) {
    dwT1[(gt % 9) * 256 + gt / 9] = dw1[gt];
    dwT2[(gt % 9) * 256 + gt / 9] = dw2[gt];
  }
  for (int e = gt; e < 65536; e += 16384) {
    pw1b[e] = f2bf(pw1[e]);
    pw2b[e] = f2bf(pw2[e]);
    wvb[e] = f2bf(wv[e]);
  }
  if (gt < 16384) {
    int o = gt >> 8;
    wqkb[gt] = f2bf(o < 32 ? wq[gt] : wk[gt - 8192]);
  }
}

// ---------------------------------------------------------------------------
// transpose x: [B][C][N] f32 -> [B][N][C] bf16  (64x64 tiles)
// ---------------------------------------------------------------------------
__global__ __launch_bounds__(256) void transpose_x(const float* __restrict__ x,
                                                   u16* __restrict__ xt) {
  __shared__ float t[64][65];
  const int b = blockIdx.z, c0 = blockIdx.y * 64, n0 = blockIdx.x * 64;
  const float* xp = x + ((size_t)b * C_ + c0) * N_ + n0;
  const int tn = threadIdx.x & 63, tc = threadIdx.x >> 6;
#pragma unroll
  for (int i = 0; i < 16; ++i)
    t[tc + 4 * i][tn] = xp[(size_t)(tc + 4 * i) * N_ + tn];
  __syncthreads();
  u16* op = xt + ((size_t)b * N_ + n0) * C_ + c0;
  const int oc = threadIdx.x & 63, on = threadIdx.x >> 6;
#pragma unroll
  for (int i = 0; i < 16; ++i)
    op[(size_t)(on + 4 * i) * C_ + oc] = f2bf(t[oc][on + 4 * i]);
}

// ---------------------------------------------------------------------------
// depthwise 3x3 NHWC bf16: src [B][N][C] -> dst [B][N][C]
// ---------------------------------------------------------------------------
__global__ __launch_bounds__(256) void dw_nhwc(const u16* __restrict__ src,
                                               const float* __restrict__ wT,
                                               u16* __restrict__ dst) {
  __shared__ float wl[9][256];
  const int b = blockIdx.y;
  for (int e = threadIdx.x; e < 2304; e += 256) wl[e >> 8][e & 255] = wT[e];
  __syncthreads();
  const int pl = threadIdx.x >> 5, c0 = (threadIdx.x & 31) * 8;
  const int p = blockIdx.x * 8 + pl;
  const int h = p >> 5, wx = p & 31;
  const u16* sp = src + (size_t)b * N_ * C_;
  float acc[8] = {0.f, 0.f, 0.f, 0.f, 0.f, 0.f, 0.f, 0.f};
#pragma unroll
  for (int dh = -1; dh <= 1; ++dh) {
    const int hh = h + dh;
    if (hh < 0 || hh > 31) continue;
#pragma unroll
    for (int dx = -1; dx <= 1; ++dx) {
      const int ww = wx + dx;
      if (ww < 0 || ww > 31) continue;
      const int k = (dh + 1) * 3 + (dx + 1);
      const uint4 v = *(const uint4*)(sp + (size_t)(hh * 32 + ww) * C_ + c0);
      const u32 vv[4] = {v.x, v.y, v.z, v.w};
#pragma unroll
      for (int j = 0; j < 4; ++j) {
        acc[2 * j] += bf2f((u16)(vv[j] & 0xffffu)) * wl[k][c0 + 2 * j];
        acc[2 * j + 1] += bf2f((u16)(vv[j] >> 16)) * wl[k][c0 + 2 * j + 1];
      }
    }
  }
  uint4 o4;
  o4.x = pack2(acc[0], acc[1]);
  o4.y = pack2(acc[2], acc[3]);
  o4.z = pack2(acc[4], acc[5]);
  o4.w = pack2(acc[6], acc[7]);
  *(uint4*)(dst + ((size_t)b * N_ + p) * C_ + c0) = o4;
}

// ---------------------------------------------------------------------------
// MFMA GEMM: Y[n][o] = epi( sum_c X[n][c] * W[o][c] ),  K = C_ = 256
// EPI 0: BN+ReLU -> bf16 NHWC (pw1)
// EPI 1: BN + x-residual -> f32 NHWC a32 (pw2)
// EPI 2: +bias -> bf16 [N][64] (qk proj)
// EPI 3: +bias -> bf16 CHW [C][N] (v proj, XA=true)
// XA: X rows feed the A operand (D rows = n). XF32: X input is f32.
// ---------------------------------------------------------------------------
template <int EPI, int BM, int BO, bool XA, bool XF32>
__global__ __launch_bounds__(256) void gemm(
    const u16* __restrict__ Xb, const float* __restrict__ Xf,
    const u16* __restrict__ Wb, const float* __restrict__ scale,
    const float* __restrict__ shift, const float* __restrict__ resid,
    u16* __restrict__ Ybf, float* __restrict__ Yf32) {
  constexpr int OL = (EPI == 2) ? 64 : C_;
  __shared__ u16 Xs[BM][72];
  __shared__ u16 Ws[BO][72];
  const int tid = threadIdx.x;
  const int b = blockIdx.z;
  const int n0 = blockIdx.x * BM, o0 = blockIdx.y * BO;
  const int wid = tid >> 6, lane = tid & 63;
  constexpr int WN = BM / 64;
  const int wn = wid % WN, wo = wid / WN;
  const int l15 = lane & 15, l4 = lane >> 4;

  v4f acc[4][4];
#pragma unroll
  for (int i = 0; i < 4; ++i)
#pragma unroll
    for (int j = 0; j < 4; ++j) acc[i][j] = v4f{0.f, 0.f, 0.f, 0.f};

  for (int k0 = 0; k0 < C_; k0 += 64) {
    for (int e = tid; e < BM * 8; e += 256) {
      const int r = e >> 3, j = e & 7;
      if constexpr (XF32) {
        const float* s = Xf + ((size_t)b * N_ + n0 + r) * C_ + k0 + j * 8;
        const float4 f0 = *(const float4*)s;
        const float4 f1 = *(const float4*)(s + 4);
        uint4 pk;
        pk.x = pack2(f0.x, f0.y);
        pk.y = pack2(f0.z, f0.w);
        pk.z = pack2(f1.x, f1.y);
        pk.w = pack2(f1.z, f1.w);
        *(uint4*)&Xs[r][j * 8] = pk;
      } else {
        *(uint4*)&Xs[r][j * 8] =
            *(const uint4*)(Xb + ((size_t)b * N_ + n0 + r) * C_ + k0 + j * 8);
      }
    }
    for (int e = tid; e < BO * 8; e += 256) {
      const int r = e >> 3, j = e & 7;
      *(uint4*)&Ws[r][j * 8] =
          *(const uint4*)(Wb + (size_t)(o0 + r) * C_ + k0 + j * 8);
    }
    __syncthreads();
#pragma unroll
    for (int ks = 0; ks < 2; ++ks) {
      v8s af[4], bf4[4];
#pragma unroll
      for (int f = 0; f < 4; ++f) {
        if constexpr (XA) {
          af[f] = *(const v8s*)&Xs[wn * 64 + f * 16 + l15][ks * 32 + l4 * 8];
          bf4[f] = *(const v8s*)&Ws[wo * 64 + f * 16 + l15][ks * 32 + l4 * 8];
        } else {
          af[f] = *(const v8s*)&Ws[wo * 64 + f * 16 + l15][ks * 32 + l4 * 8];
          bf4[f] = *(const v8s*)&Xs[wn * 64 + f * 16 + l15][ks * 32 + l4 * 8];
        }
      }
#pragma unroll
      for (int i = 0; i < 4; ++i)
#pragma unroll
        for (int j = 0; j < 4; ++j)
          acc[i][j] = __builtin_amdgcn_mfma_f32_16x16x32_bf16(
              af[i], bf4[j], acc[i][j], 0, 0, 0);
    }
    __syncthreads();
  }

#pragma unroll
  for (int i = 0; i < 4; ++i) {
#pragma unroll
    for (int j = 0; j < 4; ++j) {
      if constexpr (!XA) {
        const int o = o0 + wo * 64 + i * 16 + l4 * 4;
        const int n = n0 + wn * 64 + j * 16 + l15;
        float y0 = acc[i][j][0], y1 = acc[i][j][1];
        float y2 = acc[i][j][2], y3 = acc[i][j][3];
        if constexpr (EPI == 0 || EPI == 1) {
          const float4 sc = *(const float4*)&scale[o];
          const float4 sh = *(const float4*)&shift[o];
          y0 = y0 * sc.x + sh.x;
          y1 = y1 * sc.y + sh.y;
          y2 = y2 * sc.z + sh.z;
          y3 = y3 * sc.w + sh.w;
        }
        if constexpr (EPI == 2) {
          const float4 bi = *(const float4*)&shift[o];
          y0 += bi.x;
          y1 += bi.y;
          y2 += bi.z;
          y3 += bi.w;
        }
        if constexpr (EPI == 0) {
          y0 = fmaxf(y0, 0.f);
          y1 = fmaxf(y1, 0.f);
          y2 = fmaxf(y2, 0.f);
          y3 = fmaxf(y3, 0.f);
        }
        if constexpr (EPI == 1) {
          const size_t xb = ((size_t)b * C_ + o) * N_ + n;
          y0 += resid[xb];
          y1 += resid[xb + N_];
          y2 += resid[xb + 2 * N_];
          y3 += resid[xb + 3 * N_];
          float4 st = {y0, y1, y2, y3};
          *(float4*)&Yf32[((size_t)b * N_ + n) * C_ + o] = st;
        } else {
          uint2 st;
          st.x = pack2(y0, y1);
          st.y = pack2(y2, y3);
          *(uint2*)&Ybf[((size_t)b * N_ + n) * OL + o] = st;
        }
      } else {
        const int n = n0 + wn * 64 + i * 16 + l4 * 4;
        const int c = o0 + wo * 64 + j * 16 + l15;
        const float bi = shift[c];
        float y0 = acc[i][j][0] + bi, y1 = acc[i][j][1] + bi;
        float y2 = acc[i][j][2] + bi, y3 = acc[i][j][3] + bi;
        uint2 st;
        st.x = pack2(y0, y1);
        st.y = pack2(y2, y3);
        *(uint2*)&Ybf[((size_t)b * C_ + c) * N_ + n] = st;
      }
    }
  }
}

// ---------------------------------------------------------------------------
// flash attention: qk [B][N][64] bf16 (q cols 0-31, k cols 32-63),
// vchw [B][C][N] bf16, a32 [B][N][C] f32.
// out[b][c][m] = relu(gamma * softmax_n(q[m]·k[n]) · v[c][n] + a[m][c])
// Block: 64 m rows (16 per wave), n-tiles of 64.
// ---------------------------------------------------------------------------
__global__ __launch_bounds__(256) void flash(const u16* __restrict__ qk,
                                             const u16* __restrict__ vchw,
                                             const float* __restrict__ a32,
                                             const float* __restrict__ gamma_p,
                                             float* __restrict__ out) {
  const int b = blockIdx.y;
  const int m0 = blockIdx.x * 64;
  const int tid = threadIdx.x, wid = tid >> 6, lane = tid & 63;
  const int l15 = lane & 15, l4 = lane >> 4;
  const int mw = m0 + wid * 16;

  __shared__ u16 Vs[256][72];
  __shared__ u16 Plds[4][16][72];

  const u16* qkb = qk + (size_t)b * N_ * 64;
  const u16* vb = vchw + (size_t)b * C_ * N_;

  const v8s qf = *(const v8s*)&qkb[(size_t)(mw + l15) * 64 + l4 * 8];

  float M = -3e38f, S = 0.f;
  v4f acc[16];
#pragma unroll
  for (int i = 0; i < 16; ++i) acc[i] = v4f{0.f, 0.f, 0.f, 0.f};

  for (int n0 = 0; n0 < N_; n0 += 64) {
    __syncthreads();  // prev PV reads of Vs complete
    {
      const u16* src = vb + (size_t)tid * N_ + n0;
#pragma unroll
      for (int j = 0; j < 8; ++j)
        *(uint4*)&Vs[tid][j * 8] = *(const uint4*)(src + j * 8);
    }
    // swapped QK^T: lt[f] holds L^T[n][m], lane: m = mw+l15, n = n0+f*16+l4*4+r
    v4f lt[4];
#pragma unroll
    for (int f = 0; f < 4; ++f) {
      const v8s kf =
          *(const v8s*)&qkb[(size_t)(n0 + f * 16 + l15) * 64 + 32 + l4 * 8];
      lt[f] = __builtin_amdgcn_mfma_f32_16x16x32_bf16(
          kf, qf, v4f{0.f, 0.f, 0.f, 0.f}, 0, 0, 0);
    }
    float pmax = -3e38f;
#pragma unroll
    for (int f = 0; f < 4; ++f)
#pragma unroll
      for (int r = 0; r < 4; ++r) pmax = fmaxf(pmax, lt[f][r]);
    pmax = fmaxf(pmax, __shfl_xor(pmax, 16));
    pmax = fmaxf(pmax, __shfl_xor(pmax, 32));
    const float Mnew = fmaxf(M, pmax);
    if (__any(Mnew > M)) {
      const float fsc = __expf(M - Mnew);
      S *= fsc;
      M = Mnew;
      float fr[4];
#pragma unroll
      for (int r = 0; r < 4; ++r) fr[r] = __shfl(fsc, l4 * 4 + r);
#pragma unroll
      for (int cf = 0; cf < 16; ++cf)
#pragma unroll
        for (int r = 0; r < 4; ++r) acc[cf][r] *= fr[r];
    }
    float ssum = 0.f;
#pragma unroll
    for (int f = 0; f < 4; ++f) {
      const float p0 = __expf(lt[f][0] - M);
      const float p1 = __expf(lt[f][1] - M);
      const float p2 = __expf(lt[f][2] - M);
      const float p3 = __expf(lt[f][3] - M);
      ssum += (p0 + p1) + (p2 + p3);
      uint2 pw;
      pw.x = pack2(p0, p1);
      pw.y = pack2(p2, p3);
      *(uint2*)&Plds[wid][l15][f * 16 + l4 * 4] = pw;
    }
    S += ssum;
    __syncthreads();  // Vs staged (and own-wave P writes drained)
#pragma unroll
    for (int ks = 0; ks < 2; ++ks) {
      const v8s pa = *(const v8s*)&Plds[wid][l15][ks * 32 + l4 * 8];
#pragma unroll
      for (int cf = 0; cf < 16; ++cf) {
        const v8s vf = *(const v8s*)&Vs[cf * 16 + l15][ks * 32 + l4 * 8];
        acc[cf] = __builtin_amdgcn_mfma_f32_16x16x32_bf16(pa, vf, acc[cf], 0,
                                                          0, 0);
      }
    }
  }

  S += __shfl_xor(S, 16);
  S += __shfl_xor(S, 32);
  const float inv = 1.f / S;
  const float g = gamma_p[0];
  float invr[4];
#pragma unroll
  for (int r = 0; r < 4; ++r) invr[r] = __shfl(inv, l4 * 4 + r);
  const int mb = mw + l4 * 4;
#pragma unroll
  for (int cf = 0; cf < 16; ++cf) {
    const int c = cf * 16 + l15;
    float4 y;
    float* yp = (float*)&y;
#pragma unroll
    for (int r = 0; r < 4; ++r) {
      const float av = a32[((size_t)b * N_ + mb + r) * C_ + c];
      yp[r] = fmaxf(g * acc[cf][r] * invr[r] + av, 0.f);
    }
    *(float4*)&out[((size_t)b * C_ + c) * N_ + mb] = y;
  }
}

// ---------------------------------------------------------------------------
extern "C" void kernel_launch(void* const* d_in, const int* in_sizes, int n_in,
                              void* d_out, int out_size, void* d_ws,
                              size_t ws_size, hipStream_t stream) {
  const float* x = (const float*)d_in[0];
  const float* dw1 = (const float*)d_in[1];
  const float* pw1 = (const float*)d_in[2];
  const float* bn1g = (const float*)d_in[3];
  const float* bn1b = (const float*)d_in[4];
  const float* bn1m = (const float*)d_in[5];
  const float* bn1v = (const float*)d_in[6];
  const float* dw2 = (const float*)d_in[7];
  const float* pw2 = (const float*)d_in[8];
  const float* bn2g = (const float*)d_in[9];
  const float* bn2b = (const float*)d_in[10];
  const float* bn2m = (const float*)d_in[11];
  const float* bn2v = (const float*)d_in[12];
  const float* wq = (const float*)d_in[13];
  const float* bq = (const float*)d_in[14];
  const float* wk = (const float*)d_in[15];
  const float* bk = (const float*)d_in[16];
  const float* wv = (const float*)d_in[17];
  const float* bv = (const float*)d_in[18];
  const float* gamma = (const float*)d_in[19];
  float* out = (float*)d_out;

  char* ws = (char*)d_ws;
  size_t off = 0;
  auto alloc = [&](size_t bytes) {
    void* p = ws + off;
    off += (bytes + 255) & ~(size_t)255;
    return p;
  };
  const size_t NE = (size_t)B_ * N_ * C_;  // 16.78M elements

  float* a32 = (float*)alloc(NE * 4);           // also holds y1t (bf16) early
  u16* y1t = (u16*)a32;                         // dead before a32 is written
  u16* r1 = (u16*)alloc(NE * 2);                // xt, later t2t
  u16* r2 = (u16*)alloc(NE * 2);                // t1t, later vchw
  u16* qkbuf = (u16*)alloc((size_t)B_ * N_ * 64 * 2);
  float* scale1 = (float*)alloc(256 * 4);
  float* shift1 = (float*)alloc(256 * 4);
  float* scale2 = (float*)alloc(256 * 4);
  float* shift2 = (float*)alloc(256 * 4);
  float* bqk = (float*)alloc(64 * 4);
  float* dwT1 = (float*)alloc(2304 * 4);
  float* dwT2 = (float*)alloc(2304 * 4);
  u16* pw1b = (u16*)alloc(65536 * 2);
  u16* pw2b = (u16*)alloc(65536 * 2);
  u16* wvb = (u16*)alloc(65536 * 2);
  u16* wqkb = (u16*)alloc(16384 * 2);

  u16* xt = r1;
  u16* t1t = r2;
  u16* t2t = r1;
  u16* vchw = r2;

  prep<<<64, 256, 0, stream>>>(bn1g, bn1b, bn1m, bn1v, bn2g, bn2b, bn2m, bn2v,
                               wq, bq, wk, bk, pw1, pw2, wv, dw1, dw2, scale1,
                               shift1, scale2, shift2, bqk, dwT1, dwT2, pw1b,
                               pw2b, wvb, wqkb);
  transpose_x<<<dim3(16, 4, B_), 256, 0, stream>>>(x, xt);
  dw_nhwc<<<dim3(128, B_), 256, 0, stream>>>(xt, dwT1, t1t);
  gemm<0, 128, 128, false, false><<<dim3(8, 2, B_), 256, 0, stream>>>(
      t1t, nullptr, pw1b, scale1, shift1, nullptr, y1t, nullptr);
  dw_nhwc<<<dim3(128, B_), 256, 0, stream>>>(y1t, dwT2, t2t);
  gemm<1, 128, 128, false, false><<<dim3(8, 2, B_), 256, 0, stream>>>(
      t2t, nullptr, pw2b, scale2, shift2, x, nullptr, a32);
  gemm<2, 256, 64, false, true><<<dim3(4, 1, B_), 256, 0, stream>>>(
      nullptr, a32, wqkb, nullptr, bqk, nullptr, qkbuf, nullptr);
  gemm<3, 128, 128, true, true><<<dim3(8, 2, B_), 256, 0, stream>>>(
      nullptr, a32, wvb, nullptr, bv, nullptr, vchw, nullptr);
  flash<<<dim3(16, B_), 256, 0, stream>>>(qkbuf, vchw, a32, gamma, out);
}

// Round 3
// 259.643 us; speedup vs baseline: 5.4167x; 1.3862x over previous
//
#include <hip/hip_runtime.h>
#include <cstdint>
#include <cstddef>

#define B_ 64
#define C_ 256
#define N_ 1024

typedef short v8s __attribute__((ext_vector_type(8)));
typedef float v4f __attribute__((ext_vector_type(4)));
typedef unsigned int u32;
typedef unsigned short u16;

__device__ __forceinline__ float bf2f(u16 u) {
  return __uint_as_float(((u32)u) << 16);
}
__device__ __forceinline__ u16 f2bf(float f) {
  u32 x = __float_as_uint(f);
  x += 0x7fffu + ((x >> 16) & 1u);
  return (u16)(x >> 16);
}
__device__ __forceinline__ u32 pack2(float a, float b) {
  return (u32)f2bf(a) | ((u32)f2bf(b) << 16);
}

typedef __attribute__((address_space(3))) unsigned int lds_as_t;
typedef __attribute__((address_space(1))) const unsigned int glb_as_t;
__device__ __forceinline__ void ld_lds16(const u16* g, u16* l) {
  __builtin_amdgcn_global_load_lds((glb_as_t*)g, (lds_as_t*)l, 16, 0, 0);
}

// ---------------------------------------------------------------------------
// prep: BN folding, weight casts / concat / transposes
// ---------------------------------------------------------------------------
__global__ __launch_bounds__(256) void prep(
    const float* __restrict__ g1, const float* __restrict__ b1,
    const float* __restrict__ m1, const float* __restrict__ v1,
    const float* __restrict__ g2, const float* __restrict__ b2,
    const float* __restrict__ m2, const float* __restrict__ v2,
    const float* __restrict__ wq, const float* __restrict__ bq,
    const float* __restrict__ wk, const float* __restrict__ bk,
    const float* __restrict__ wv, const float* __restrict__ bv,
    const float* __restrict__ pw1, const float* __restrict__ pw2,
    const float* __restrict__ dw1, const float* __restrict__ dw2,
    float* __restrict__ scale1, float* __restrict__ shift1,
    float* __restrict__ scale2, float* __restrict__ shift2,
    float* __restrict__ dwT1, float* __restrict__ dwT2,
    u16* __restrict__ pw1b, u16* __restrict__ pw2b, u16* __restrict__ wcatb,
    float* __restrict__ bcat) {
  const int gt = blockIdx.x * 256 + threadIdx.x;  // 16384 threads
  if (gt < 256) {
    float s1 = g1[gt] * rsqrtf(v1[gt] + 1e-5f);
    scale1[gt] = s1;
    shift1[gt] = b1[gt] - m1[gt] * s1;
    float s2 = g2[gt] * rsqrtf(v2[gt] + 1e-5f);
    scale2[gt] = s2;
    shift2[gt] = b2[gt] - m2[gt] * s2;
  }
  if (gt < 320) bcat[gt] = (gt < 32) ? bq[gt] : (gt < 64) ? bk[gt - 32] : bv[gt - 64];
  if (gt < 2304) {
    dwT1[(gt % 9) * 256 + gt / 9] = dw1[gt];
    dwT2[(gt % 9) * 256 + gt / 9] = dw2[gt];
  }
  for (int e = gt; e < 65536; e += 16384) {
    pw1b[e] = f2bf(pw1[e]);
    pw2b[e] = f2bf(pw2[e]);
  }
  for (int e = gt; e < 81920; e += 16384) {
    const int o = e >> 8;
    float w = (o < 32) ? wq[e] : (o < 64) ? wk[e - 8192] : wv[e - 16384];
    wcatb[e] = f2bf(w);
  }
}

// ---------------------------------------------------------------------------
// transpose x: [B][C][N] f32 -> [B][N][C] bf16  (64x64 tiles)
// ---------------------------------------------------------------------------
__global__ __launch_bounds__(256) void transpose_x(const float* __restrict__ x,
                                                   u16* __restrict__ xt) {
  __shared__ float t[64][65];
  const int b = blockIdx.z, c0 = blockIdx.y * 64, n0 = blockIdx.x * 64;
  const float* xp = x + ((size_t)b * C_ + c0) * N_ + n0;
  const int tn = threadIdx.x & 63, tc = threadIdx.x >> 6;
#pragma unroll
  for (int i = 0; i < 16; ++i)
    t[tc + 4 * i][tn] = xp[(size_t)(tc + 4 * i) * N_ + tn];
  __syncthreads();
  u16* op = xt + ((size_t)b * N_ + n0) * C_ + c0;
  const int oc = threadIdx.x & 63, on = threadIdx.x >> 6;
#pragma unroll
  for (int i = 0; i < 16; ++i)
    op[(size_t)(on + 4 * i) * C_ + oc] = f2bf(t[oc][on + 4 * i]);
}

// ---------------------------------------------------------------------------
// depthwise 3x3 NHWC bf16: src [B][N][C] -> dst [B][N][C]
// ---------------------------------------------------------------------------
__global__ __launch_bounds__(256) void dw_nhwc(const u16* __restrict__ src,
                                               const float* __restrict__ wT,
                                               u16* __restrict__ dst) {
  __shared__ float wl[9][256];
  const int b = blockIdx.y;
  for (int e = threadIdx.x; e < 2304; e += 256) wl[e >> 8][e & 255] = wT[e];
  __syncthreads();
  const int pl = threadIdx.x >> 5, c0 = (threadIdx.x & 31) * 8;
  const int p = blockIdx.x * 8 + pl;
  const int h = p >> 5, wx = p & 31;
  const u16* sp = src + (size_t)b * N_ * C_;
  float acc[8] = {0.f, 0.f, 0.f, 0.f, 0.f, 0.f, 0.f, 0.f};
#pragma unroll
  for (int dh = -1; dh <= 1; ++dh) {
    const int hh = h + dh;
    if (hh < 0 || hh > 31) continue;
#pragma unroll
    for (int dx = -1; dx <= 1; ++dx) {
      const int ww = wx + dx;
      if (ww < 0 || ww > 31) continue;
      const int k = (dh + 1) * 3 + (dx + 1);
      const uint4 v = *(const uint4*)(sp + (size_t)(hh * 32 + ww) * C_ + c0);
      const u32 vv[4] = {v.x, v.y, v.z, v.w};
#pragma unroll
      for (int j = 0; j < 4; ++j) {
        acc[2 * j] += bf2f((u16)(vv[j] & 0xffffu)) * wl[k][c0 + 2 * j];
        acc[2 * j + 1] += bf2f((u16)(vv[j] >> 16)) * wl[k][c0 + 2 * j + 1];
      }
    }
  }
  uint4 o4;
  o4.x = pack2(acc[0], acc[1]);
  o4.y = pack2(acc[2], acc[3]);
  o4.z = pack2(acc[4], acc[5]);
  o4.w = pack2(acc[6], acc[7]);
  *(uint4*)(dst + ((size_t)b * N_ + p) * C_ + c0) = o4;
}

// ---------------------------------------------------------------------------
// MFMA GEMM (m97-style global_load_lds staging):
//   Y[n][o] = epi( sum_c X[n][c] * W[o][c] ), K = 256, tiles 128x128
// EPI 0: BN+ReLU -> bf16 NHWC (pw1)
// EPI 1: BN + bf16-NHWC residual -> bf16 NHWC (pw2)
// EPI 2: fused qkv: o<64 -> qk [n][64]; 64<=o<320 -> v CHW [o-64][n]
// ---------------------------------------------------------------------------
template <int EPI>
__global__ __launch_bounds__(256) void gemm(
    const u16* __restrict__ X, const u16* __restrict__ W,
    const float* __restrict__ scale, const float* __restrict__ shift,
    const u16* __restrict__ resid, u16* __restrict__ Y, u16* __restrict__ Y2) {
  __shared__ u16 Xs[128][64];
  __shared__ u16 Ws[128][64];
  const int tid = threadIdx.x;
  const int b = blockIdx.z;
  const int n0 = blockIdx.x * 128, o0 = blockIdx.y * 128;
  const int wid = tid >> 6, lane = tid & 63;
  const int wn = wid & 1, wo = wid >> 1;
  const int l15 = lane & 15, l4 = lane >> 4;
  const int lr = lane >> 3, lc = (lane & 7) * 8;  // staging: row-sub, col

  v4f acc[4][4];
#pragma unroll
  for (int i = 0; i < 4; ++i)
#pragma unroll
    for (int j = 0; j < 4; ++j) acc[i][j] = v4f{0.f, 0.f, 0.f, 0.f};

  for (int k0 = 0; k0 < C_; k0 += 64) {
    // stage X tile rows [wid*32 .. +32), W tile likewise; 4 instrs each
#pragma unroll
    for (int g = 0; g < 4; ++g) {
      const int base = wid * 32 + g * 8;
      const int xr = n0 + base + lr;
      ld_lds16(X + ((size_t)b * N_ + xr) * C_ + k0 + lc, &Xs[base][0]);
      int wr = o0 + base + lr;
      if (EPI == 2 && wr > 319) wr = 319;
      ld_lds16(W + (size_t)wr * C_ + k0 + lc, &Ws[base][0]);
    }
    __syncthreads();
#pragma unroll
    for (int ks = 0; ks < 2; ++ks) {
      v8s af[4], bf4[4];
#pragma unroll
      for (int f = 0; f < 4; ++f) {
        af[f] = *(const v8s*)&Ws[wo * 64 + f * 16 + l15][ks * 32 + l4 * 8];
        bf4[f] = *(const v8s*)&Xs[wn * 64 + f * 16 + l15][ks * 32 + l4 * 8];
      }
#pragma unroll
      for (int i = 0; i < 4; ++i)
#pragma unroll
        for (int j = 0; j < 4; ++j)
          acc[i][j] = __builtin_amdgcn_mfma_f32_16x16x32_bf16(
              af[i], bf4[j], acc[i][j], 0, 0, 0);
    }
    __syncthreads();
  }

#pragma unroll
  for (int i = 0; i < 4; ++i) {
    const int obase = o0 + wo * 64 + i * 16 + l4 * 4;
#pragma unroll
    for (int j = 0; j < 4; ++j) {
      const int n = n0 + wn * 64 + j * 16 + l15;
      float y0 = acc[i][j][0], y1 = acc[i][j][1];
      float y2 = acc[i][j][2], y3 = acc[i][j][3];
      if constexpr (EPI == 0 || EPI == 1) {
        const float4 sc = *(const float4*)&scale[obase];
        const float4 sh = *(const float4*)&shift[obase];
        y0 = y0 * sc.x + sh.x;
        y1 = y1 * sc.y + sh.y;
        y2 = y2 * sc.z + sh.z;
        y3 = y3 * sc.w + sh.w;
        if constexpr (EPI == 0) {
          y0 = fmaxf(y0, 0.f);
          y1 = fmaxf(y1, 0.f);
          y2 = fmaxf(y2, 0.f);
          y3 = fmaxf(y3, 0.f);
        } else {
          const uint2 rb =
              *(const uint2*)(resid + ((size_t)b * N_ + n) * C_ + obase);
          y0 += bf2f((u16)(rb.x & 0xffffu));
          y1 += bf2f((u16)(rb.x >> 16));
          y2 += bf2f((u16)(rb.y & 0xffffu));
          y3 += bf2f((u16)(rb.y >> 16));
        }
        uint2 st;
        st.x = pack2(y0, y1);
        st.y = pack2(y2, y3);
        *(uint2*)&Y[((size_t)b * N_ + n) * C_ + obase] = st;
      } else {
        if (obase >= 320) continue;
        const float4 bi = *(const float4*)&shift[obase];
        y0 += bi.x;
        y1 += bi.y;
        y2 += bi.z;
        y3 += bi.w;
        if (obase < 64) {
          uint2 st;
          st.x = pack2(y0, y1);
          st.y = pack2(y2, y3);
          *(uint2*)&Y[((size_t)b * N_ + n) * 64 + obase] = st;
        } else {
          const int c = obase - 64;
          Y2[((size_t)b * C_ + c) * N_ + n] = f2bf(y0);
          Y2[((size_t)b * C_ + c + 1) * N_ + n] = f2bf(y1);
          Y2[((size_t)b * C_ + c + 2) * N_ + n] = f2bf(y2);
          Y2[((size_t)b * C_ + c + 3) * N_ + n] = f2bf(y3);
        }
      }
    }
  }
}

// ---------------------------------------------------------------------------
// flash attention v2: qk [B][N][64] bf16 (q cols 0-31, k cols 32-63),
// vchw [B][C][N] bf16, abf [B][N][C] bf16 residual.
// Double-buffered V via global_load_lds with pre-swizzled source; K-frag
// register prefetch one tile ahead; 1 barrier/tile.
// ---------------------------------------------------------------------------
__global__ __launch_bounds__(256) void flash(const u16* __restrict__ qk,
                                             const u16* __restrict__ vchw,
                                             const u16* __restrict__ abf,
                                             const float* __restrict__ gamma_p,
                                             float* __restrict__ out) {
  const int b = blockIdx.y;
  const int m0 = blockIdx.x * 64;
  const int tid = threadIdx.x, wid = tid >> 6, lane = tid & 63;
  const int l15 = lane & 15, l4 = lane >> 4;
  const int mw = m0 + wid * 16;

  __shared__ u16 Vs[2][256][64];   // swizzled: logical slot j at phys j^(c&7)
  __shared__ u16 Plds[4][16][72];  // per-wave private

  const u16* qkb = qk + (size_t)b * N_ * 64;
  const u16* vb = vchw + (size_t)b * C_ * N_;

  const v8s qf = *(const v8s*)&qkb[(size_t)(mw + l15) * 64 + l4 * 8];

  // staging lane mapping: c = base + (lane>>3), phys slot = lane&7,
  // logical slot = (lane&7) ^ (c&7)  ->  global col = logical*8
  const int src_c = lane >> 3;
  const int src_j = (lane & 7) ^ (lane >> 3);

  // prologue: stage tile 0, prefetch K-frags for tile 0
  v8s kf[4];
#pragma unroll
  for (int g = 0; g < 8; ++g) {
    const int base = wid * 64 + g * 8;
    ld_lds16(vb + (size_t)(base + src_c) * N_ + src_j * 8, &Vs[0][base][0]);
  }
#pragma unroll
  for (int f = 0; f < 4; ++f)
    kf[f] = *(const v8s*)&qkb[(size_t)(f * 16 + l15) * 64 + 32 + l4 * 8];
  __syncthreads();  // drains vmcnt(0): tile-0 V staged, kf loaded

  float M = -3e38f, S = 0.f;
  v4f acc[16];
#pragma unroll
  for (int i = 0; i < 16; ++i) acc[i] = v4f{0.f, 0.f, 0.f, 0.f};

  for (int t = 0; t < 16; ++t) {
    const int cur = t & 1;
    // QK^T from prefetched K-frags (swapped: D[n][m])
    v4f lt[4];
#pragma unroll
    for (int f = 0; f < 4; ++f)
      lt[f] = __builtin_amdgcn_mfma_f32_16x16x32_bf16(
          kf[f], qf, v4f{0.f, 0.f, 0.f, 0.f}, 0, 0, 0);
    // issue next tile's V stage + K prefetch (drained at end-of-iter barrier)
    if (t < 15) {
      const int n1 = (t + 1) * 64;
#pragma unroll
      for (int g = 0; g < 8; ++g) {
        const int base = wid * 64 + g * 8;
        ld_lds16(vb + (size_t)(base + src_c) * N_ + n1 + src_j * 8,
                 &Vs[cur ^ 1][base][0]);
      }
#pragma unroll
      for (int f = 0; f < 4; ++f)
        kf[f] = *(const v8s*)&qkb[(size_t)(n1 + f * 16 + l15) * 64 + 32 +
                                  l4 * 8];
    }
    // online softmax (stats per m-row = l15; 4 dup lanes in l4)
    float pmax = -3e38f;
#pragma unroll
    for (int f = 0; f < 4; ++f)
#pragma unroll
      for (int r = 0; r < 4; ++r) pmax = fmaxf(pmax, lt[f][r]);
    pmax = fmaxf(pmax, __shfl_xor(pmax, 16));
    pmax = fmaxf(pmax, __shfl_xor(pmax, 32));
    const float Mnew = fmaxf(M, pmax);
    if (__any(Mnew > M)) {
      const float fsc = __expf(M - Mnew);
      S *= fsc;
      M = Mnew;
      float fr[4];
#pragma unroll
      for (int r = 0; r < 4; ++r) fr[r] = __shfl(fsc, l4 * 4 + r);
#pragma unroll
      for (int cf = 0; cf < 16; ++cf)
#pragma unroll
        for (int r = 0; r < 4; ++r) acc[cf][r] *= fr[r];
    }
    float ssum = 0.f;
#pragma unroll
    for (int f = 0; f < 4; ++f) {
      const float p0 = __expf(lt[f][0] - M);
      const float p1 = __expf(lt[f][1] - M);
      const float p2 = __expf(lt[f][2] - M);
      const float p3 = __expf(lt[f][3] - M);
      ssum += (p0 + p1) + (p2 + p3);
      uint2 pw;
      pw.x = pack2(p0, p1);
      pw.y = pack2(p2, p3);
      *(uint2*)&Plds[wid][l15][f * 16 + l4 * 4] = pw;  // wave-private
    }
    S += ssum;
    // PV: P from wave-private LDS (lgkm-ordered), V from swizzled Vs[cur]
#pragma unroll
    for (int ks = 0; ks < 2; ++ks) {
      const v8s pa = *(const v8s*)&Plds[wid][l15][ks * 32 + l4 * 8];
#pragma unroll
      for (int cf = 0; cf < 16; ++cf) {
        const int col = 8 * (((ks * 4) + l4) ^ (l15 & 7));
        const v8s vf = *(const v8s*)&Vs[cur][cf * 16 + l15][col];
        acc[cf] = __builtin_amdgcn_mfma_f32_16x16x32_bf16(pa, vf, acc[cf], 0,
                                                          0, 0);
      }
    }
    __syncthreads();  // drain next-tile staging; protect Vs[cur] for reuse
  }

  S += __shfl_xor(S, 16);
  S += __shfl_xor(S, 32);
  const float inv = 1.f / S;
  const float g = gamma_p[0];
  float invr[4];
#pragma unroll
  for (int r = 0; r < 4; ++r) invr[r] = __shfl(inv, l4 * 4 + r);
  const int mb = mw + l4 * 4;
#pragma unroll
  for (int cf = 0; cf < 16; ++cf) {
    const int c = cf * 16 + l15;
    float4 y;
    float* yp = (float*)&y;
#pragma unroll
    for (int r = 0; r < 4; ++r) {
      const float av = bf2f(abf[((size_t)b * N_ + mb + r) * C_ + c]);
      yp[r] = fmaxf(g * acc[cf][r] * invr[r] + av, 0.f);
    }
    *(float4*)&out[((size_t)b * C_ + c) * N_ + mb] = y;
  }
}

// ---------------------------------------------------------------------------
extern "C" void kernel_launch(void* const* d_in, const int* in_sizes, int n_in,
                              void* d_out, int out_size, void* d_ws,
                              size_t ws_size, hipStream_t stream) {
  const float* x = (const float*)d_in[0];
  const float* dw1 = (const float*)d_in[1];
  const float* pw1 = (const float*)d_in[2];
  const float* bn1g = (const float*)d_in[3];
  const float* bn1b = (const float*)d_in[4];
  const float* bn1m = (const float*)d_in[5];
  const float* bn1v = (const float*)d_in[6];
  const float* dw2 = (const float*)d_in[7];
  const float* pw2 = (const float*)d_in[8];
  const float* bn2g = (const float*)d_in[9];
  const float* bn2b = (const float*)d_in[10];
  const float* bn2m = (const float*)d_in[11];
  const float* bn2v = (const float*)d_in[12];
  const float* wq = (const float*)d_in[13];
  const float* bq = (const float*)d_in[14];
  const float* wk = (const float*)d_in[15];
  const float* bk = (const float*)d_in[16];
  const float* wv = (const float*)d_in[17];
  const float* bv = (const float*)d_in[18];
  const float* gamma = (const float*)d_in[19];
  float* out = (float*)d_out;

  char* ws = (char*)d_ws;
  size_t off = 0;
  auto alloc = [&](size_t bytes) {
    void* p = ws + off;
    off += (bytes + 255) & ~(size_t)255;
    return p;
  };
  const size_t NE = (size_t)B_ * N_ * C_;  // 16.78M elements

  u16* bufA = (u16*)alloc(NE * 2);  // xt, later vchw
  u16* bufB = (u16*)alloc(NE * 2);  // t1, later t2
  u16* bufC = (u16*)alloc(NE * 2);  // y1, later qk
  u16* abf = (u16*)alloc(NE * 2);
  float* scale1 = (float*)alloc(256 * 4);
  float* shift1 = (float*)alloc(256 * 4);
  float* scale2 = (float*)alloc(256 * 4);
  float* shift2 = (float*)alloc(256 * 4);
  float* dwT1 = (float*)alloc(2304 * 4);
  float* dwT2 = (float*)alloc(2304 * 4);
  u16* pw1b = (u16*)alloc(65536 * 2);
  u16* pw2b = (u16*)alloc(65536 * 2);
  u16* wcatb = (u16*)alloc(81920 * 2);
  float* bcat = (float*)alloc(320 * 4);

  u16* xt = bufA;
  u16* t1 = bufB;
  u16* y1 = bufC;
  u16* t2 = bufB;
  u16* qkbuf = bufC;
  u16* vchw = bufA;

  prep<<<64, 256, 0, stream>>>(bn1g, bn1b, bn1m, bn1v, bn2g, bn2b, bn2m, bn2v,
                               wq, bq, wk, bk, wv, bv, pw1, pw2, dw1, dw2,
                               scale1, shift1, scale2, shift2, dwT1, dwT2,
                               pw1b, pw2b, wcatb, bcat);
  transpose_x<<<dim3(16, 4, B_), 256, 0, stream>>>(x, xt);
  dw_nhwc<<<dim3(128, B_), 256, 0, stream>>>(xt, dwT1, t1);
  gemm<0><<<dim3(8, 2, B_), 256, 0, stream>>>(t1, pw1b, scale1, shift1,
                                              nullptr, y1, nullptr);
  dw_nhwc<<<dim3(128, B_), 256, 0, stream>>>(y1, dwT2, t2);
  gemm<1><<<dim3(8, 2, B_), 256, 0, stream>>>(t2, pw2b, scale2, shift2, xt,
                                              abf, nullptr);
  gemm<2><<<dim3(8, 3, B_), 256, 0, stream>>>(abf, wcatb, nullptr, bcat,
                                              nullptr, qkbuf, vchw);
  flash<<<dim3(16, B_), 256, 0, stream>>>(qkbuf, vchw, abf, gamma, out);
}

// Round 4
// 258.174 us; speedup vs baseline: 5.4475x; 1.0057x over previous
//
#include <hip/hip_runtime.h>
#include <cstdint>
#include <cstddef>

#define B_ 64
#define C_ 256
#define N_ 1024
#define LOG2E 1.4426950408889634f

typedef short v8s __attribute__((ext_vector_type(8)));
typedef float v4f __attribute__((ext_vector_type(4)));
typedef unsigned int u32;
typedef unsigned short u16;

__device__ __forceinline__ float bf2f(u16 u) {
  return __uint_as_float(((u32)u) << 16);
}
__device__ __forceinline__ u16 f2bf(float f) {
  u32 x = __float_as_uint(f);
  x += 0x7fffu + ((x >> 16) & 1u);
  return (u16)(x >> 16);
}
__device__ __forceinline__ u32 pack2(float a, float b) {
  return (u32)f2bf(a) | ((u32)f2bf(b) << 16);
}

typedef __attribute__((address_space(3))) unsigned int lds_as_t;
typedef __attribute__((address_space(1))) const unsigned int glb_as_t;
__device__ __forceinline__ void ld_lds16(const u16* g, u16* l) {
  __builtin_amdgcn_global_load_lds((glb_as_t*)g, (lds_as_t*)l, 16, 0, 0);
}

// ---------------------------------------------------------------------------
// prep: BN folding, weight casts / concat / transposes. q pre-scaled by log2e
// so flash can use exp2 directly.
// ---------------------------------------------------------------------------
__global__ __launch_bounds__(256) void prep(
    const float* __restrict__ g1, const float* __restrict__ b1,
    const float* __restrict__ m1, const float* __restrict__ v1,
    const float* __restrict__ g2, const float* __restrict__ b2,
    const float* __restrict__ m2, const float* __restrict__ v2,
    const float* __restrict__ wq, const float* __restrict__ bq,
    const float* __restrict__ wk, const float* __restrict__ bk,
    const float* __restrict__ wv, const float* __restrict__ bv,
    const float* __restrict__ pw1, const float* __restrict__ pw2,
    const float* __restrict__ dw1, const float* __restrict__ dw2,
    float* __restrict__ scale1, float* __restrict__ shift1,
    float* __restrict__ scale2, float* __restrict__ shift2,
    float* __restrict__ dwT1, float* __restrict__ dwT2,
    u16* __restrict__ pw1b, u16* __restrict__ pw2b, u16* __restrict__ wcatb,
    float* __restrict__ bcat) {
  const int gt = blockIdx.x * 256 + threadIdx.x;  // 16384 threads
  if (gt < 256) {
    float s1 = g1[gt] * rsqrtf(v1[gt] + 1e-5f);
    scale1[gt] = s1;
    shift1[gt] = b1[gt] - m1[gt] * s1;
    float s2 = g2[gt] * rsqrtf(v2[gt] + 1e-5f);
    scale2[gt] = s2;
    shift2[gt] = b2[gt] - m2[gt] * s2;
  }
  if (gt < 320)
    bcat[gt] = (gt < 32) ? bq[gt] * LOG2E
                         : (gt < 64) ? bk[gt - 32] : bv[gt - 64];
  if (gt < 2304) {
    dwT1[(gt % 9) * 256 + gt / 9] = dw1[gt];
    dwT2[(gt % 9) * 256 + gt / 9] = dw2[gt];
  }
  for (int e = gt; e < 65536; e += 16384) {
    pw1b[e] = f2bf(pw1[e]);
    pw2b[e] = f2bf(pw2[e]);
  }
  for (int e = gt; e < 81920; e += 16384) {
    const int o = e >> 8;
    float w = (o < 32) ? wq[e] * LOG2E
                       : (o < 64) ? wk[e - 8192] : wv[e - 16384];
    wcatb[e] = f2bf(w);
  }
}

// ---------------------------------------------------------------------------
// transpose x: [B][C][N] f32 -> [B][N][C] bf16  (64x64 tiles)
// ---------------------------------------------------------------------------
__global__ __launch_bounds__(256) void transpose_x(const float* __restrict__ x,
                                                   u16* __restrict__ xt) {
  __shared__ float t[64][65];
  const int b = blockIdx.z, c0 = blockIdx.y * 64, n0 = blockIdx.x * 64;
  const float* xp = x + ((size_t)b * C_ + c0) * N_ + n0;
  const int tn = threadIdx.x & 63, tc = threadIdx.x >> 6;
#pragma unroll
  for (int i = 0; i < 16; ++i)
    t[tc + 4 * i][tn] = xp[(size_t)(tc + 4 * i) * N_ + tn];
  __syncthreads();
  u16* op = xt + ((size_t)b * N_ + n0) * C_ + c0;
  const int oc = threadIdx.x & 63, on = threadIdx.x >> 6;
#pragma unroll
  for (int i = 0; i < 16; ++i)
    op[(size_t)(on + 4 * i) * C_ + oc] = f2bf(t[oc][on + 4 * i]);
}

// ---------------------------------------------------------------------------
// depthwise 3x3 NHWC bf16: src [B][N][C] -> dst [B][N][C]
// ---------------------------------------------------------------------------
__global__ __launch_bounds__(256) void dw_nhwc(const u16* __restrict__ src,
                                               const float* __restrict__ wT,
                                               u16* __restrict__ dst) {
  __shared__ float wl[9][256];
  const int b = blockIdx.y;
  for (int e = threadIdx.x; e < 2304; e += 256) wl[e >> 8][e & 255] = wT[e];
  __syncthreads();
  const int pl = threadIdx.x >> 5, c0 = (threadIdx.x & 31) * 8;
  const int p = blockIdx.x * 8 + pl;
  const int h = p >> 5, wx = p & 31;
  const u16* sp = src + (size_t)b * N_ * C_;
  float acc[8] = {0.f, 0.f, 0.f, 0.f, 0.f, 0.f, 0.f, 0.f};
#pragma unroll
  for (int dh = -1; dh <= 1; ++dh) {
    const int hh = h + dh;
    if (hh < 0 || hh > 31) continue;
#pragma unroll
    for (int dx = -1; dx <= 1; ++dx) {
      const int ww = wx + dx;
      if (ww < 0 || ww > 31) continue;
      const int k = (dh + 1) * 3 + (dx + 1);
      const uint4 v = *(const uint4*)(sp + (size_t)(hh * 32 + ww) * C_ + c0);
      const u32 vv[4] = {v.x, v.y, v.z, v.w};
#pragma unroll
      for (int j = 0; j < 4; ++j) {
        acc[2 * j] += bf2f((u16)(vv[j] & 0xffffu)) * wl[k][c0 + 2 * j];
        acc[2 * j + 1] += bf2f((u16)(vv[j] >> 16)) * wl[k][c0 + 2 * j + 1];
      }
    }
  }
  uint4 o4;
  o4.x = pack2(acc[0], acc[1]);
  o4.y = pack2(acc[2], acc[3]);
  o4.z = pack2(acc[4], acc[5]);
  o4.w = pack2(acc[6], acc[7]);
  *(uint4*)(dst + ((size_t)b * N_ + p) * C_ + c0) = o4;
}

// ---------------------------------------------------------------------------
// MFMA GEMM with LDS-bounce coalesced epilogue.
//   Y[n][o] = epi( sum_c X[n][c] * W[o][c] ), K = 256, tiles 128x128
// EPI 0: BN+ReLU -> bf16 NHWC (pw1)
// EPI 1: BN + bf16-NHWC residual -> bf16 NHWC (pw2)
// EPI 2: fused qkv (operands swapped so D rows = n):
//        o<64 -> qk [n][64] direct stores; 64<=o<320 -> v CHW via bounce
// ---------------------------------------------------------------------------
template <int EPI>
__global__ __launch_bounds__(256) void gemm(
    const u16* __restrict__ X, const u16* __restrict__ W,
    const float* __restrict__ scale, const float* __restrict__ shift,
    const u16* __restrict__ resid, u16* __restrict__ Y, u16* __restrict__ Y2) {
  __shared__ u16 smem[17408];  // max(Xs+Ws = 32KB, Ys = 34KB)
  u16(*Xs)[64] = (u16(*)[64])smem;
  u16(*Ws)[64] = (u16(*)[64])(smem + 8192);
  u16(*Ys)[136] = (u16(*)[136])smem;

  const int tid = threadIdx.x;
  const int b = blockIdx.z;
  const int n0 = blockIdx.x * 128, o0 = blockIdx.y * 128;
  const int wid = tid >> 6, lane = tid & 63;
  const int wn = wid & 1, wo = wid >> 1;
  const int l15 = lane & 15, l4 = lane >> 4;
  const int lr = lane >> 3, lc = (lane & 7) * 8;

  v4f acc[4][4];
#pragma unroll
  for (int i = 0; i < 4; ++i)
#pragma unroll
    for (int j = 0; j < 4; ++j) acc[i][j] = v4f{0.f, 0.f, 0.f, 0.f};

  for (int k0 = 0; k0 < C_; k0 += 64) {
#pragma unroll
    for (int g = 0; g < 4; ++g) {
      const int base = wid * 32 + g * 8;
      ld_lds16(X + ((size_t)b * N_ + n0 + base + lr) * C_ + k0 + lc,
               &Xs[base][0]);
      int wr = o0 + base + lr;
      if (EPI == 2 && wr > 319) wr = 319;
      ld_lds16(W + (size_t)wr * C_ + k0 + lc, &Ws[base][0]);
    }
    __syncthreads();
#pragma unroll
    for (int ks = 0; ks < 2; ++ks) {
      v8s af[4], bf4[4];
#pragma unroll
      for (int f = 0; f < 4; ++f) {
        if constexpr (EPI != 2) {
          af[f] = *(const v8s*)&Ws[wo * 64 + f * 16 + l15][ks * 32 + l4 * 8];
          bf4[f] = *(const v8s*)&Xs[wn * 64 + f * 16 + l15][ks * 32 + l4 * 8];
        } else {
          af[f] = *(const v8s*)&Xs[wn * 64 + f * 16 + l15][ks * 32 + l4 * 8];
          bf4[f] = *(const v8s*)&Ws[wo * 64 + f * 16 + l15][ks * 32 + l4 * 8];
        }
      }
#pragma unroll
      for (int i = 0; i < 4; ++i)
#pragma unroll
        for (int j = 0; j < 4; ++j)
          acc[i][j] = __builtin_amdgcn_mfma_f32_16x16x32_bf16(
              af[i], bf4[j], acc[i][j], 0, 0, 0);
    }
    __syncthreads();
  }

  if constexpr (EPI != 2) {
    // D rows = o (l4*4+r), cols = n (l15). Pack to Ys[n][o], store rows.
#pragma unroll
    for (int i = 0; i < 4; ++i) {
      const int oL = wo * 64 + i * 16 + l4 * 4;
      const int o = o0 + oL;
      const float4 sc = *(const float4*)&scale[o];
      const float4 sh = *(const float4*)&shift[o];
#pragma unroll
      for (int j = 0; j < 4; ++j) {
        const int nL = wn * 64 + j * 16 + l15;
        float y0 = acc[i][j][0] * sc.x + sh.x;
        float y1 = acc[i][j][1] * sc.y + sh.y;
        float y2 = acc[i][j][2] * sc.z + sh.z;
        float y3 = acc[i][j][3] * sc.w + sh.w;
        if constexpr (EPI == 0) {
          y0 = fmaxf(y0, 0.f);
          y1 = fmaxf(y1, 0.f);
          y2 = fmaxf(y2, 0.f);
          y3 = fmaxf(y3, 0.f);
        } else {
          const uint2 rb =
              *(const uint2*)(resid + ((size_t)b * N_ + n0 + nL) * C_ + o);
          y0 += bf2f((u16)(rb.x & 0xffffu));
          y1 += bf2f((u16)(rb.x >> 16));
          y2 += bf2f((u16)(rb.y & 0xffffu));
          y3 += bf2f((u16)(rb.y >> 16));
        }
        uint2 st;
        st.x = pack2(y0, y1);
        st.y = pack2(y2, y3);
        *(uint2*)&Ys[nL][oL] = st;
      }
    }
    __syncthreads();
#pragma unroll
    for (int s = 0; s < 8; ++s) {
      const int nL = s * 16 + (tid >> 4);
      const int slot = tid & 15;
      const uint4 v = *(const uint4*)&Ys[nL][slot * 8];
      *(uint4*)&Y[((size_t)b * N_ + n0 + nL) * C_ + o0 + slot * 8] = v;
    }
  } else {
    // D rows = n (l4*4+r), cols = o (l15).
    float bj[4];
#pragma unroll
    for (int j = 0; j < 4; ++j) {
      int o = o0 + wo * 64 + j * 16 + l15;
      bj[j] = shift[o > 319 ? 319 : o];
    }
    if (o0 == 0 && wo == 0) {
      // qk part: o = j*16+l15 < 64, direct scalar stores (small)
#pragma unroll
      for (int i = 0; i < 4; ++i) {
        const int nB = n0 + wn * 64 + i * 16 + l4 * 4;
#pragma unroll
        for (int j = 0; j < 4; ++j) {
          const int o = j * 16 + l15;
#pragma unroll
          for (int r = 0; r < 4; ++r)
            Y[((size_t)b * N_ + nB + r) * 64 + o] = f2bf(acc[i][j][r] + bj[j]);
        }
      }
    } else {
      // v part: pack to Ys[o][n]
#pragma unroll
      for (int i = 0; i < 4; ++i) {
        const int nL = wn * 64 + i * 16 + l4 * 4;
#pragma unroll
        for (int j = 0; j < 4; ++j) {
          const int oL = wo * 64 + j * 16 + l15;
          uint2 st;
          st.x = pack2(acc[i][j][0] + bj[j], acc[i][j][1] + bj[j]);
          st.y = pack2(acc[i][j][2] + bj[j], acc[i][j][3] + bj[j]);
          *(uint2*)&Ys[oL][nL] = st;
        }
      }
    }
    __syncthreads();
#pragma unroll
    for (int s = 0; s < 8; ++s) {
      const int oL = s * 16 + (tid >> 4);
      const int c = o0 + oL - 64;
      if (c >= 0 && c < 256) {
        const int slot = tid & 15;
        const uint4 v = *(const uint4*)&Ys[oL][slot * 8];
        *(uint4*)&Y2[((size_t)b * C_ + c) * N_ + n0 + slot * 8] = v;
      }
    }
  }
}

// ---------------------------------------------------------------------------
// flash attention v3 (two-pass fixed-max, log2-domain):
// qk [B][N][64] bf16 (q cols 0-31 pre-scaled by log2e, k cols 32-63),
// vchw [B][C][N] bf16, abf [B][N][C] bf16 residual.
// Pass 1: exact row max via recomputed QK^T (no per-tile cross-lane ops).
// Pass 2: p = exp2(lt - M), PV with double-buffered V (global_load_lds).
// Grid (b, m): same-b blocks land on one XCD (linear id % 8 == b % 8).
// ---------------------------------------------------------------------------
__global__ __launch_bounds__(256) void flash(const u16* __restrict__ qk,
                                             const u16* __restrict__ vchw,
                                             const u16* __restrict__ abf,
                                             const float* __restrict__ gamma_p,
                                             float* __restrict__ out) {
  const int b = blockIdx.x;
  const int m0 = blockIdx.y * 64;
  const int tid = threadIdx.x, wid = tid >> 6, lane = tid & 63;
  const int l15 = lane & 15, l4 = lane >> 4;
  const int mw = m0 + wid * 16;

  __shared__ u16 Vs[2][256][64];   // swizzled: logical slot j at phys j^(c&7)
  __shared__ u16 Plds[4][16][72];  // per-wave private

  const u16* qkb = qk + (size_t)b * N_ * 64;
  const u16* vb = vchw + (size_t)b * C_ * N_;
  const v8s qf = *(const v8s*)&qkb[(size_t)(mw + l15) * 64 + l4 * 8];

  const int src_c = lane >> 3;
  const int src_j = (lane & 7) ^ (lane >> 3);

  // stage V tile 0 early (drained at the pre-pass2 barrier)
#pragma unroll
  for (int g = 0; g < 8; ++g) {
    const int base = wid * 64 + g * 8;
    ld_lds16(vb + (size_t)(base + src_c) * N_ + src_j * 8, &Vs[0][base][0]);
  }

  // ---- pass 1: exact row max ----
  float Mloc = -3e38f;
  v8s kf[4];
#pragma unroll
  for (int f = 0; f < 4; ++f)
    kf[f] = *(const v8s*)&qkb[(size_t)(f * 16 + l15) * 64 + 32 + l4 * 8];
  for (int t = 0; t < 16; ++t) {
    v8s kn[4];
    if (t < 15) {
      const int n1 = (t + 1) * 64;
#pragma unroll
      for (int f = 0; f < 4; ++f)
        kn[f] =
            *(const v8s*)&qkb[(size_t)(n1 + f * 16 + l15) * 64 + 32 + l4 * 8];
    }
#pragma unroll
    for (int f = 0; f < 4; ++f) {
      const v4f lt = __builtin_amdgcn_mfma_f32_16x16x32_bf16(
          kf[f], qf, v4f{0.f, 0.f, 0.f, 0.f}, 0, 0, 0);
      Mloc = fmaxf(Mloc, fmaxf(fmaxf(lt[0], lt[1]), fmaxf(lt[2], lt[3])));
    }
    if (t < 15) {
#pragma unroll
      for (int f = 0; f < 4; ++f) kf[f] = kn[f];
    }
  }
  Mloc = fmaxf(Mloc, __shfl_xor(Mloc, 16));
  Mloc = fmaxf(Mloc, __shfl_xor(Mloc, 32));
  const float M = Mloc;

  // ---- pass 2: exp2 + PV ----
  v4f acc[16];
#pragma unroll
  for (int i = 0; i < 16; ++i) acc[i] = v4f{0.f, 0.f, 0.f, 0.f};
  float S0 = 0.f, S1 = 0.f, S2 = 0.f, S3 = 0.f;
#pragma unroll
  for (int f = 0; f < 4; ++f)
    kf[f] = *(const v8s*)&qkb[(size_t)(f * 16 + l15) * 64 + 32 + l4 * 8];
  __syncthreads();  // V tile 0 staged, kf ready

  for (int t = 0; t < 16; ++t) {
    const int cur = t & 1;
    v4f lt[4];
#pragma unroll
    for (int f = 0; f < 4; ++f)
      lt[f] = __builtin_amdgcn_mfma_f32_16x16x32_bf16(
          kf[f], qf, v4f{0.f, 0.f, 0.f, 0.f}, 0, 0, 0);
    if (t < 15) {
      const int n1 = (t + 1) * 64;
#pragma unroll
      for (int g = 0; g < 8; ++g) {
        const int base = wid * 64 + g * 8;
        ld_lds16(vb + (size_t)(base + src_c) * N_ + n1 + src_j * 8,
                 &Vs[cur ^ 1][base][0]);
      }
#pragma unroll
      for (int f = 0; f < 4; ++f)
        kf[f] =
            *(const v8s*)&qkb[(size_t)(n1 + f * 16 + l15) * 64 + 32 + l4 * 8];
    }
#pragma unroll
    for (int f = 0; f < 4; ++f) {
      const float p0 = exp2f(lt[f][0] - M);
      const float p1 = exp2f(lt[f][1] - M);
      const float p2 = exp2f(lt[f][2] - M);
      const float p3 = exp2f(lt[f][3] - M);
      S0 += p0;
      S1 += p1;
      S2 += p2;
      S3 += p3;
      uint2 pw;
      pw.x = pack2(p0, p1);
      pw.y = pack2(p2, p3);
      *(uint2*)&Plds[wid][l15][f * 16 + l4 * 4] = pw;  // wave-private
    }
    __builtin_amdgcn_s_setprio(1);
#pragma unroll
    for (int ks = 0; ks < 2; ++ks) {
      const v8s pa = *(const v8s*)&Plds[wid][l15][ks * 32 + l4 * 8];
#pragma unroll
      for (int cf = 0; cf < 16; ++cf) {
        const int col = 8 * (((ks * 4) + l4) ^ (l15 & 7));
        const v8s vf = *(const v8s*)&Vs[cur][cf * 16 + l15][col];
        acc[cf] = __builtin_amdgcn_mfma_f32_16x16x32_bf16(pa, vf, acc[cf], 0,
                                                          0, 0);
      }
    }
    __builtin_amdgcn_s_setprio(0);
    __syncthreads();  // drain next-tile staging; protect Vs[cur]
  }

  float S = (S0 + S1) + (S2 + S3);
  S += __shfl_xor(S, 16);
  S += __shfl_xor(S, 32);
  const float inv = 1.f / S;
  const float g = gamma_p[0];
  float invr[4];
#pragma unroll
  for (int r = 0; r < 4; ++r) invr[r] = __shfl(inv, l4 * 4 + r);
  const int mb = mw + l4 * 4;
#pragma unroll
  for (int cf = 0; cf < 16; ++cf) {
    const int c = cf * 16 + l15;
    float4 y;
    float* yp = (float*)&y;
#pragma unroll
    for (int r = 0; r < 4; ++r) {
      const float av = bf2f(abf[((size_t)b * N_ + mb + r) * C_ + c]);
      yp[r] = fmaxf(g * acc[cf][r] * invr[r] + av, 0.f);
    }
    *(float4*)&out[((size_t)b * C_ + c) * N_ + mb] = y;
  }
}

// ---------------------------------------------------------------------------
extern "C" void kernel_launch(void* const* d_in, const int* in_sizes, int n_in,
                              void* d_out, int out_size, void* d_ws,
                              size_t ws_size, hipStream_t stream) {
  const float* x = (const float*)d_in[0];
  const float* dw1 = (const float*)d_in[1];
  const float* pw1 = (const float*)d_in[2];
  const float* bn1g = (const float*)d_in[3];
  const float* bn1b = (const float*)d_in[4];
  const float* bn1m = (const float*)d_in[5];
  const float* bn1v = (const float*)d_in[6];
  const float* dw2 = (const float*)d_in[7];
  const float* pw2 = (const float*)d_in[8];
  const float* bn2g = (const float*)d_in[9];
  const float* bn2b = (const float*)d_in[10];
  const float* bn2m = (const float*)d_in[11];
  const float* bn2v = (const float*)d_in[12];
  const float* wq = (const float*)d_in[13];
  const float* bq = (const float*)d_in[14];
  const float* wk = (const float*)d_in[15];
  const float* bk = (const float*)d_in[16];
  const float* wv = (const float*)d_in[17];
  const float* bv = (const float*)d_in[18];
  const float* gamma = (const float*)d_in[19];
  float* out = (float*)d_out;

  char* ws = (char*)d_ws;
  size_t off = 0;
  auto alloc = [&](size_t bytes) {
    void* p = ws + off;
    off += (bytes + 255) & ~(size_t)255;
    return p;
  };
  const size_t NE = (size_t)B_ * N_ * C_;  // 16.78M elements

  u16* bufA = (u16*)alloc(NE * 2);  // xt, later vchw
  u16* bufB = (u16*)alloc(NE * 2);  // t1, later t2
  u16* bufC = (u16*)alloc(NE * 2);  // y1, later qk
  u16* abf = (u16*)alloc(NE * 2);
  float* scale1 = (float*)alloc(256 * 4);
  float* shift1 = (float*)alloc(256 * 4);
  float* scale2 = (float*)alloc(256 * 4);
  float* shift2 = (float*)alloc(256 * 4);
  float* dwT1 = (float*)alloc(2304 * 4);
  float* dwT2 = (float*)alloc(2304 * 4);
  u16* pw1b = (u16*)alloc(65536 * 2);
  u16* pw2b = (u16*)alloc(65536 * 2);
  u16* wcatb = (u16*)alloc(81920 * 2);
  float* bcat = (float*)alloc(384 * 4);

  u16* xt = bufA;
  u16* t1 = bufB;
  u16* y1 = bufC;
  u16* t2 = bufB;
  u16* qkbuf = bufC;
  u16* vchw = bufA;

  prep<<<64, 256, 0, stream>>>(bn1g, bn1b, bn1m, bn1v, bn2g, bn2b, bn2m, bn2v,
                               wq, bq, wk, bk, wv, bv, pw1, pw2, dw1, dw2,
                               scale1, shift1, scale2, shift2, dwT1, dwT2,
                               pw1b, pw2b, wcatb, bcat);
  transpose_x<<<dim3(16, 4, B_), 256, 0, stream>>>(x, xt);
  dw_nhwc<<<dim3(128, B_), 256, 0, stream>>>(xt, dwT1, t1);
  gemm<0><<<dim3(8, 2, B_), 256, 0, stream>>>(t1, pw1b, scale1, shift1,
                                              nullptr, y1, nullptr);
  dw_nhwc<<<dim3(128, B_), 256, 0, stream>>>(y1, dwT2, t2);
  gemm<1><<<dim3(8, 2, B_), 256, 0, stream>>>(t2, pw2b, scale2, shift2, xt,
                                              abf, nullptr);
  gemm<2><<<dim3(8, 3, B_), 256, 0, stream>>>(abf, wcatb, nullptr, bcat,
                                              nullptr, qkbuf, vchw);
  flash<<<dim3(64, 16), 256, 0, stream>>>(qkbuf, vchw, abf, gamma, out);
}